// Round 19
// baseline (6221.184 us; speedup 1.0000x reference)
//
#include <hip/hip_runtime.h>
#include <hip/hip_bf16.h>

// RNN: h_t = tanh(x_t @ Wx + h_{t-1} @ Wh + b), B=32, S=1024, D=H=1024, fp32.
// Phase 1: Xp = x@Wx + b in-place into d_out (~87% of fp32 vector peak).
// Phase 2: ONE persistent kernel, 8 chains x 32 WGs x (4b x 32n).
// R19 = R16 (bit30 tag-in-data, replay-proven BEST at 4.86ms) + stale-masked
//   re-poll: first poll pass = R16's full parallel 8-load batch; retry rounds
//   reload ONLY stale words (typically 1-4) -> 2-8x less MALL storm traffic
//   while waiting + shorter retry rounds. No new phases (R17 lesson), no
//   sleep quantization, protocol byte-identical.
//   R18 lesson: Xp double-buffer + split-half poll both neutral-to-negative
//   (added phases/VGPR for off-path latency) -> reverted to R16 base.

#define BB 32
#define SS 1024
#define DD 1024
#define HH 1024
#define NG 32   // n-groups of 32 cols
#define BG 8    // b-groups (chains) of 4 batches
#define WGN (NG * BG)

typedef unsigned long long ull;

#define ALD(p) __hip_atomic_load((p), __ATOMIC_RELAXED, __HIP_MEMORY_SCOPE_AGENT)

// ---------------- Phase 1: C = A @ W + bias ----------------
__global__ __launch_bounds__(256) void xw_gemm(const float* __restrict__ A,
                                               const float* __restrict__ W,
                                               const float* __restrict__ bias,
                                               float* __restrict__ C) {
    __shared__ float As[8][132];
    __shared__ float Bs[8][132];
    const int tid = threadIdx.x;
    const int n0 = blockIdx.x * 128;
    const int m0 = blockIdx.y * 128;
    const int tx = tid & 15;
    const int ty = tid >> 4;
    const int ar = tid >> 1;
    const int ak = (tid & 1) * 4;
    const int bk = tid >> 5;
    const int bn = (tid & 31) * 4;

    float acc[8][8];
#pragma unroll
    for (int i = 0; i < 8; ++i)
#pragma unroll
        for (int j = 0; j < 8; ++j) acc[i][j] = 0.f;

    for (int k0 = 0; k0 < DD; k0 += 8) {
        float4 av = *(const float4*)(A + (size_t)(m0 + ar) * DD + k0 + ak);
        float4 bv = *(const float4*)(W + (size_t)(k0 + bk) * HH + n0 + bn);
        __syncthreads();
        As[ak + 0][ar] = av.x;
        As[ak + 1][ar] = av.y;
        As[ak + 2][ar] = av.z;
        As[ak + 3][ar] = av.w;
        *(float4*)&Bs[bk][bn] = bv;
        __syncthreads();
#pragma unroll
        for (int k = 0; k < 8; ++k) {
            float4 a0 = *(const float4*)&As[k][ty * 4];
            float4 a1 = *(const float4*)&As[k][64 + ty * 4];
            float4 b0 = *(const float4*)&Bs[k][tx * 4];
            float4 b1 = *(const float4*)&Bs[k][64 + tx * 4];
            float ar_[8] = {a0.x, a0.y, a0.z, a0.w, a1.x, a1.y, a1.z, a1.w};
            float br_[8] = {b0.x, b0.y, b0.z, b0.w, b1.x, b1.y, b1.z, b1.w};
#pragma unroll
            for (int i = 0; i < 8; ++i)
#pragma unroll
                for (int j = 0; j < 8; ++j)
                    acc[i][j] = fmaf(ar_[i], br_[j], acc[i][j]);
        }
    }

    float4 bv0 = *(const float4*)(bias + n0 + tx * 4);
    float4 bv1 = *(const float4*)(bias + n0 + 64 + tx * 4);
#pragma unroll
    for (int i = 0; i < 8; ++i) {
        int m = m0 + ((i < 4) ? (ty * 4 + i) : (64 + ty * 4 + (i - 4)));
        float4 r0 = {acc[i][0] + bv0.x, acc[i][1] + bv0.y,
                     acc[i][2] + bv0.z, acc[i][3] + bv0.w};
        float4 r1 = {acc[i][4] + bv1.x, acc[i][5] + bv1.y,
                     acc[i][6] + bv1.z, acc[i][7] + bv1.w};
        *(float4*)(C + (size_t)m * HH + n0 + tx * 4) = r0;
        *(float4*)(C + (size_t)m * HH + n0 + 64 + tx * 4) = r1;
    }
}

// ---------------- WhT[n][k] = Wh[k][n] ----------------
__global__ __launch_bounds__(256) void transpose_wh(const float* __restrict__ in,
                                                    float* __restrict__ outT) {
    __shared__ float tile[32][33];
    const int tx = threadIdx.x & 31;
    const int ty = threadIdx.x >> 5;
    const int x0 = blockIdx.x * 32;
    const int y0 = blockIdx.y * 32;
    for (int r = ty; r < 32; r += 8)
        tile[r][tx] = in[(size_t)(y0 + r) * HH + x0 + tx];
    __syncthreads();
    for (int r = ty; r < 32; r += 8)
        outT[(size_t)(x0 + r) * HH + y0 + tx] = tile[tx][r];
}

// ---------------- Persistent RNN over all S steps ----------------
// WG(bg,ng): batches b0..b0+3, cols n0..n0+31. Thread tile 4b x 16n x 8k:
//   ns = tid>>7 (col half of 16), kq = tid&127 -> k in {4kq..+3} u {512+4kq..+3}.
#define FMA_HALF(HALF)                                                         \
    {                                                                          \
        const int kb = (HALF) * 512 + kq * 4;                                  \
        float4 h[4];                                                           \
        _Pragma("unroll") for (int b = 0; b < 4; ++b)                          \
            h[b] = *(const float4*)&hs[b][kb];                                 \
        _Pragma("unroll") for (int b = 0; b < 4; ++b)                          \
            _Pragma("unroll") for (int c = 0; c < 16; ++c)                     \
                a[b * 16 + c] += h[b].x * wreg[HALF][c].x +                    \
                                 h[b].y * wreg[HALF][c].y +                    \
                                 h[b].z * wreg[HALF][c].z +                    \
                                 h[b].w * wreg[HALF][c].w;                     \
    }

__global__ __launch_bounds__(256, 1) void rnn_persist(
    const float* __restrict__ Wh, const float* __restrict__ WhT,
    const float* __restrict__ h0, float* __restrict__ out,
    float* __restrict__ hbuf) {
    __shared__ float hs[4][1024];    // 16KB [b][k]
    __shared__ float red[4][64];
    __shared__ float hout[4][32];    // linearized h tile for coalesced publish

    const int tid  = threadIdx.x;
    const int ng   = blockIdx.x & 31;
    const int bg   = blockIdx.x >> 5;
    const int n0   = ng * 32;
    const int b0   = bg * 4;
    const int lane = tid & 63;
    const int wv   = tid >> 6;
    const int ns   = tid >> 7;
    const int kq   = tid & 127;

    const ull TAGMASK = ~((1ull << 30) | (1ull << 62));

    // --- one-time: this thread's Wh fragment into registers ---
    float4 wreg[2][16];
    if (WhT) {
        const float* base = WhT + (size_t)(n0 + ns * 16) * HH + kq * 4;
#pragma unroll
        for (int c = 0; c < 16; ++c) {
            wreg[0][c] = *(const float4*)(base + (size_t)c * HH);
            wreg[1][c] = *(const float4*)(base + (size_t)c * HH + 512);
        }
    } else {
#pragma unroll
        for (int c = 0; c < 16; ++c) {
            float v[8];
            for (int j = 0; j < 4; ++j)
                v[j] = Wh[(size_t)(kq * 4 + j) * HH + n0 + ns * 16 + c];
            for (int j = 0; j < 4; ++j)
                v[4 + j] = Wh[(size_t)(512 + kq * 4 + j) * HH + n0 + ns * 16 + c];
            wreg[0][c] = {v[0], v[1], v[2], v[3]};
            wreg[1][c] = {v[4], v[5], v[6], v[7]};
        }
    }

    // epilogue mapping: thread (tid<128) owns output (eb, ec)
    size_t xp_base = 0;
    int eb = 0, ec = 0;
    if (tid < 128) {
        int l   = tid & 63;
        int idx = (int)(__brev((unsigned)l) >> 26);  // 6-bit bit-reverse
        eb = idx >> 4;                                // 0..3
        ec = (tid >> 6) * 16 + (idx & 15);            // 0..31
        xp_base = ((size_t)(b0 + eb) * SS) * HH + (n0 + ec);
    }

    for (int t = 0; t < SS; ++t) {
        // ---- prefetch own Xp (plain load, independent of sync) ----
        float xp = 0.f;
        if (tid < 128) xp = out[xp_base + (size_t)t * HH];

        float a[64];
#pragma unroll
        for (int i = 0; i < 64; ++i) a[i] = 0.f;

        if (t == 0) {
#pragma unroll
            for (int j = 0; j < 4; ++j) {
                int f4 = tid + 256 * j;
                int r = f4 >> 8, c4 = (f4 & 255) * 4;
                *(float4*)&hs[r][c4] = *(const float4*)(h0 + c4);
            }
            __syncthreads();
            FMA_HALF(0)
            FMA_HALF(1)
        } else {
            // ---- tag-in-data poll. First pass: full parallel 8-load batch
            //      (R16 fast path). Retry: reload ONLY stale words. ----
            const ull* hsrc = (const ull*)hbuf + (size_t)((t - 1) & 1) * BB * 512;
            const unsigned pc = ((unsigned)(t - 1) >> 1) & 1u;
            const ull* p[8];
#pragma unroll
            for (int j = 0; j < 4; ++j) {
                p[j]     = hsrc + (size_t)(b0 + j) * 512 + tid;
                p[4 + j] = hsrc + (size_t)(b0 + j) * 512 + 256 + tid;
            }
            ull w[8];
            unsigned good = 0;
#pragma unroll
            for (int j = 0; j < 8; ++j) w[j] = ALD(p[j]);
#pragma unroll
            for (int j = 0; j < 8; ++j) {
                unsigned ok = ((((unsigned)(w[j] >> 30)) ^ pc) & 1u) |
                              ((((unsigned)(w[j] >> 62)) ^ pc) & 1u);
                good |= (ok == 0u ? 1u : 0u) << j;
            }
            while (good != 0xFFu) {
#pragma unroll
                for (int j = 0; j < 8; ++j) {
                    if (!(good & (1u << j))) {
                        ull v = ALD(p[j]);
                        unsigned ok = ((((unsigned)(v >> 30)) ^ pc) & 1u) |
                                      ((((unsigned)(v >> 62)) ^ pc) & 1u);
                        if (ok == 0u) {
                            w[j] = v;
                            good |= 1u << j;
                        }
                    }
                }
            }
#pragma unroll
            for (int j = 0; j < 4; ++j) {
                *(ull*)&hs[j][tid * 2] = w[j] & TAGMASK;
                *(ull*)&hs[j][512 + tid * 2] = w[4 + j] & TAGMASK;
            }
            __syncthreads();
            FMA_HALF(0)
            FMA_HALF(1)
        }

        // ---- folding in-wave reduce over kq ----
        int s = 64;
#pragma unroll
        for (int m = 1; m <= 32; m <<= 1) {
            const int hs_ = s >> 1;
            const bool hi = (lane & m) != 0;
#pragma unroll
            for (int i = 0; i < hs_; ++i) {
                float lo = a[i], hg = a[i + hs_];
                a[i]       = hi ? hg : lo;
                a[i + hs_] = hi ? lo : hg;
            }
#pragma unroll
            for (int i = 0; i < hs_; ++i) a[i] += __shfl_xor(a[i + hs_], m, 64);
            s = hs_;
        }

        red[wv][lane] = a[0];
        __syncthreads();

        // ---- epilogue: finalize, write out (plain), linearize into hout ----
        if (tid < 128) {
            const int l = tid & 63;
            const int nss = tid >> 6;
            float v = red[nss * 2][l] + red[nss * 2 + 1][l];
            float hv = tanhf(v + xp);
            out[xp_base + (size_t)t * HH] = hv;  // plain (write-only in-kernel)
            hout[eb][ec] = hv;
        }
        __syncthreads();

        // ---- publish: 64 contiguous 8B stores, bit30 of each float = step
        //      parity (t>>1)&1 (R16's proven form) ----
        if (tid < 64) {
            const int r  = tid >> 4;   // 0..3
            const int c2 = tid & 15;   // 0..15 (x2 floats = 32 cols)
            const ull pp = (ull)(((unsigned)t >> 1) & 1u);
            ull u = *(const ull*)&hout[r][c2 * 2];
            u |= (pp << 30) | (pp << 62);
            __hip_atomic_store(
                (ull*)hbuf + (size_t)(t & 1) * BB * 512 +
                    (size_t)(b0 + r) * 512 + (n0 >> 1) + c2,
                u, __ATOMIC_RELAXED, __HIP_MEMORY_SCOPE_AGENT);
        }
        // no trailing barrier: next step's tag-poll self-validates.
    }
}

// ---------------- fallback path (tiny ws): multi-launch steps ----------------
__global__ __launch_bounds__(256) void h0wh(const float* __restrict__ Wh,
                                            const float* __restrict__ h0,
                                            float* __restrict__ c) {
    const int g = blockIdx.x;
    const int n = threadIdx.x * 4;
    float4 a = {0.f, 0.f, 0.f, 0.f};
    for (int kk = 0; kk < 16; ++kk) {
        int k = g * 16 + kk;
        float hv = h0[k];
        float4 w = *(const float4*)(Wh + (size_t)k * HH + n);
        a.x += hv * w.x; a.y += hv * w.y; a.z += hv * w.z; a.w += hv * w.w;
    }
    atomicAdd(&c[n + 0], a.x);
    atomicAdd(&c[n + 1], a.y);
    atomicAdd(&c[n + 2], a.z);
    atomicAdd(&c[n + 3], a.w);
}

__global__ __launch_bounds__(256) void t0_kernel(float* __restrict__ out,
                                                 const float* __restrict__ c) {
    const int idx = blockIdx.x * 256 + threadIdx.x;
    const int b = idx >> 10;
    const int n = idx & 1023;
    const size_t p = (size_t)b * SS * HH + n;
    out[p] = tanhf(out[p] + c[n]);
}

__global__ __launch_bounds__(256) void rnn_step(const float* __restrict__ Wh,
                                                float* __restrict__ out, int t) {
    __shared__ float hsl[8][1028];
    __shared__ float ps[256];
    const int tid = threadIdx.x;
    const int n0 = blockIdx.x * 16;
    const int b0 = blockIdx.y * 8;
    for (int i = tid; i < 8 * 256; i += 256) {
        int r = i >> 8;
        int c = (i & 255) << 2;
        *(float4*)&hsl[r][c] =
            *(const float4*)(out + ((size_t)(b0 + r) * SS + (t - 1)) * HH + c);
    }
    __syncthreads();
    const int nl = tid & 15;
    const int bl = (tid >> 4) & 7;
    const int half_ = tid >> 7;
    const int n = n0 + nl;
    float acc = 0.f;
    const float* hrow = &hsl[bl][half_ * 512];
    const float* wcol = Wh + (size_t)(half_ * 512) * HH + n;
#pragma unroll 4
    for (int k = 0; k < 512; k += 4) {
        float4 h4 = *(const float4*)(hrow + k);
        acc += h4.x * wcol[(size_t)(k + 0) * HH];
        acc += h4.y * wcol[(size_t)(k + 1) * HH];
        acc += h4.z * wcol[(size_t)(k + 2) * HH];
        acc += h4.w * wcol[(size_t)(k + 3) * HH];
    }
    ps[tid] = acc;
    __syncthreads();
    if (tid < 128) {
        const size_t obase = ((size_t)(b0 + bl) * SS + t) * HH + n;
        out[obase] = tanhf(out[obase] + ps[tid] + ps[tid + 128]);
    }
}

extern "C" void kernel_launch(void* const* d_in, const int* in_sizes, int n_in,
                              void* d_out, int out_size, void* d_ws, size_t ws_size,
                              hipStream_t stream) {
    const float* x    = (const float*)d_in[0];
    const float* Wx   = (const float*)d_in[1];
    const float* Wh   = (const float*)d_in[2];
    const float* bias = (const float*)d_in[3];
    const float* h0   = (const float*)d_in[4];
    float* out = (float*)d_out;
    float* ws  = (float*)d_ws;

    // Phase 1: Xp = x@Wx + b -> d_out
    xw_gemm<<<dim3(8, 256), 256, 0, stream>>>(x, Wx, bias, out);

    // ws layout: hbuf 2*32*1024 floats (256 KB, tag-in-data) | WhT 1024^2 f
    const size_t need_persist = (size_t)(2 * BB * HH) * sizeof(float);
    const size_t need_wht     = need_persist + (size_t)HH * HH * sizeof(float);

    if (ws_size >= need_persist) {
        float* hbuf = ws;
        // erase stale tags from prior launches/poison: 0xFF -> bit30=1 = stale
        hipMemsetAsync(hbuf, 0xFF, need_persist, stream);

        const float* WhT = nullptr;
        if (ws_size >= need_wht) {
            float* whtp = ws + 2 * BB * HH;
            transpose_wh<<<dim3(32, 32), 256, 0, stream>>>(Wh, whtp);
            WhT = whtp;
        }

        void* kargs[] = {(void*)&Wh, (void*)&WhT, (void*)&h0, (void*)&out,
                         (void*)&hbuf};
        hipError_t rc = hipLaunchCooperativeKernel((const void*)rnn_persist,
                                                   dim3(WGN), dim3(256), kargs, 0,
                                                   stream);
        if (rc != hipSuccess) {
            rnn_persist<<<dim3(WGN), dim3(256), 0, stream>>>(Wh, WhT, h0, out,
                                                             hbuf);
        }
    } else {
        // emergency fallback: multi-launch (correct, slow)
        float* cvec = ws;  // 1024 floats
        hipMemsetAsync(cvec, 0, HH * sizeof(float), stream);
        h0wh<<<64, 256, 0, stream>>>(Wh, h0, cvec);
        t0_kernel<<<BB * HH / 256, 256, 0, stream>>>(out, cvec);
        for (int t = 1; t < SS; ++t)
            rnn_step<<<dim3(64, 4), 256, 0, stream>>>(Wh, out, t);
    }
}

// Round 20
// 4858.043 us; speedup vs baseline: 1.2806x; 1.2806x over previous
//
#include <hip/hip_runtime.h>
#include <hip/hip_bf16.h>

// RNN: h_t = tanh(x_t @ Wx + h_{t-1} @ Wh + b), B=32, S=1024, D=H=1024, fp32.
// FINAL = R16 (best measured: 4.86 ms total, replay-proven).
// Phase 1: Xp = x@Wx + b in-place into d_out (~87% of fp32 vector peak).
// Phase 2: ONE persistent kernel, 8 chains x 32 WGs x (4b x 32n).
//   BIT30 TAG-IN-DATA sync: h = tanh(.) in [-1,1] -> bit30 of every published
//   float is 0. Publisher sets bit30 = (t>>1)&1; consumer polls the data
//   words themselves (single parallel 8-load batch per round) until parity
//   matches, then clears bit30 (exact recovery). Validity is atomic WITHIN
//   each word -> no flag, no ack, no ordering assumptions; hoisted or stale
//   reads simply fail parity and retry. 2-slot ping-pong bounds skew < 2
//   steps so parity disambiguates; memset 0xFF erases stale tags per launch.
// Lessons encoded from rounds 17-19 (all regressed; do not revisit):
//   - sampled gate / split-phase polls SERIALIZE wait phases -> slower
//   - stale-masked re-poll diverges exec mask -> serialized loads -> slower
//   - per-chain counter/flag gates (R12/R15) = same speed, more complexity
//   - agent-RELEASE/acquire = buffer_wbl2/inv storms (R2/R4: 3-10x slower)
//   - sc0 "L2-local" polling deadlocks (L1-served stale lines, R13)
//   - 2-chain interleave serializes phases in-stream (R14: +21%)

#define BB 32
#define SS 1024
#define DD 1024
#define HH 1024
#define NG 32   // n-groups of 32 cols
#define BG 8    // b-groups (chains) of 4 batches
#define WGN (NG * BG)

typedef unsigned long long ull;

#define ALD(p) __hip_atomic_load((p), __ATOMIC_RELAXED, __HIP_MEMORY_SCOPE_AGENT)

// ---------------- Phase 1: C = A @ W + bias ----------------
__global__ __launch_bounds__(256) void xw_gemm(const float* __restrict__ A,
                                               const float* __restrict__ W,
                                               const float* __restrict__ bias,
                                               float* __restrict__ C) {
    __shared__ float As[8][132];
    __shared__ float Bs[8][132];
    const int tid = threadIdx.x;
    const int n0 = blockIdx.x * 128;
    const int m0 = blockIdx.y * 128;
    const int tx = tid & 15;
    const int ty = tid >> 4;
    const int ar = tid >> 1;
    const int ak = (tid & 1) * 4;
    const int bk = tid >> 5;
    const int bn = (tid & 31) * 4;

    float acc[8][8];
#pragma unroll
    for (int i = 0; i < 8; ++i)
#pragma unroll
        for (int j = 0; j < 8; ++j) acc[i][j] = 0.f;

    for (int k0 = 0; k0 < DD; k0 += 8) {
        float4 av = *(const float4*)(A + (size_t)(m0 + ar) * DD + k0 + ak);
        float4 bv = *(const float4*)(W + (size_t)(k0 + bk) * HH + n0 + bn);
        __syncthreads();
        As[ak + 0][ar] = av.x;
        As[ak + 1][ar] = av.y;
        As[ak + 2][ar] = av.z;
        As[ak + 3][ar] = av.w;
        *(float4*)&Bs[bk][bn] = bv;
        __syncthreads();
#pragma unroll
        for (int k = 0; k < 8; ++k) {
            float4 a0 = *(const float4*)&As[k][ty * 4];
            float4 a1 = *(const float4*)&As[k][64 + ty * 4];
            float4 b0 = *(const float4*)&Bs[k][tx * 4];
            float4 b1 = *(const float4*)&Bs[k][64 + tx * 4];
            float ar_[8] = {a0.x, a0.y, a0.z, a0.w, a1.x, a1.y, a1.z, a1.w};
            float br_[8] = {b0.x, b0.y, b0.z, b0.w, b1.x, b1.y, b1.z, b1.w};
#pragma unroll
            for (int i = 0; i < 8; ++i)
#pragma unroll
                for (int j = 0; j < 8; ++j)
                    acc[i][j] = fmaf(ar_[i], br_[j], acc[i][j]);
        }
    }

    float4 bv0 = *(const float4*)(bias + n0 + tx * 4);
    float4 bv1 = *(const float4*)(bias + n0 + 64 + tx * 4);
#pragma unroll
    for (int i = 0; i < 8; ++i) {
        int m = m0 + ((i < 4) ? (ty * 4 + i) : (64 + ty * 4 + (i - 4)));
        float4 r0 = {acc[i][0] + bv0.x, acc[i][1] + bv0.y,
                     acc[i][2] + bv0.z, acc[i][3] + bv0.w};
        float4 r1 = {acc[i][4] + bv1.x, acc[i][5] + bv1.y,
                     acc[i][6] + bv1.z, acc[i][7] + bv1.w};
        *(float4*)(C + (size_t)m * HH + n0 + tx * 4) = r0;
        *(float4*)(C + (size_t)m * HH + n0 + 64 + tx * 4) = r1;
    }
}

// ---------------- WhT[n][k] = Wh[k][n] ----------------
__global__ __launch_bounds__(256) void transpose_wh(const float* __restrict__ in,
                                                    float* __restrict__ outT) {
    __shared__ float tile[32][33];
    const int tx = threadIdx.x & 31;
    const int ty = threadIdx.x >> 5;
    const int x0 = blockIdx.x * 32;
    const int y0 = blockIdx.y * 32;
    for (int r = ty; r < 32; r += 8)
        tile[r][tx] = in[(size_t)(y0 + r) * HH + x0 + tx];
    __syncthreads();
    for (int r = ty; r < 32; r += 8)
        outT[(size_t)(x0 + r) * HH + y0 + tx] = tile[tx][r];
}

// ---------------- Persistent RNN over all S steps ----------------
// WG(bg,ng): batches b0..b0+3, cols n0..n0+31. Thread tile 4b x 16n x 8k:
//   ns = tid>>7 (col half of 16), kq = tid&127 -> k in {4kq..+3} u {512+4kq..+3}.
#define FMA_HALF(HALF)                                                         \
    {                                                                          \
        const int kb = (HALF) * 512 + kq * 4;                                  \
        float4 h[4];                                                           \
        _Pragma("unroll") for (int b = 0; b < 4; ++b)                          \
            h[b] = *(const float4*)&hs[b][kb];                                 \
        _Pragma("unroll") for (int b = 0; b < 4; ++b)                          \
            _Pragma("unroll") for (int c = 0; c < 16; ++c)                     \
                a[b * 16 + c] += h[b].x * wreg[HALF][c].x +                    \
                                 h[b].y * wreg[HALF][c].y +                    \
                                 h[b].z * wreg[HALF][c].z +                    \
                                 h[b].w * wreg[HALF][c].w;                     \
    }

__global__ __launch_bounds__(256, 1) void rnn_persist(
    const float* __restrict__ Wh, const float* __restrict__ WhT,
    const float* __restrict__ h0, float* __restrict__ out,
    float* __restrict__ hbuf) {
    __shared__ float hs[4][1024];    // 16KB [b][k]
    __shared__ float red[4][64];
    __shared__ float hout[4][32];    // linearized h tile for coalesced publish

    const int tid  = threadIdx.x;
    const int ng   = blockIdx.x & 31;
    const int bg   = blockIdx.x >> 5;
    const int n0   = ng * 32;
    const int b0   = bg * 4;
    const int lane = tid & 63;
    const int wv   = tid >> 6;
    const int ns   = tid >> 7;
    const int kq   = tid & 127;

    const ull TAGMASK = ~((1ull << 30) | (1ull << 62));

    // --- one-time: this thread's Wh fragment into registers ---
    float4 wreg[2][16];
    if (WhT) {
        const float* base = WhT + (size_t)(n0 + ns * 16) * HH + kq * 4;
#pragma unroll
        for (int c = 0; c < 16; ++c) {
            wreg[0][c] = *(const float4*)(base + (size_t)c * HH);
            wreg[1][c] = *(const float4*)(base + (size_t)c * HH + 512);
        }
    } else {
#pragma unroll
        for (int c = 0; c < 16; ++c) {
            float v[8];
            for (int j = 0; j < 4; ++j)
                v[j] = Wh[(size_t)(kq * 4 + j) * HH + n0 + ns * 16 + c];
            for (int j = 0; j < 4; ++j)
                v[4 + j] = Wh[(size_t)(512 + kq * 4 + j) * HH + n0 + ns * 16 + c];
            wreg[0][c] = {v[0], v[1], v[2], v[3]};
            wreg[1][c] = {v[4], v[5], v[6], v[7]};
        }
    }

    // epilogue mapping: thread (tid<128) owns output (eb, ec)
    size_t xp_base = 0;
    int eb = 0, ec = 0;
    if (tid < 128) {
        int l   = tid & 63;
        int idx = (int)(__brev((unsigned)l) >> 26);  // 6-bit bit-reverse
        eb = idx >> 4;                                // 0..3
        ec = (tid >> 6) * 16 + (idx & 15);            // 0..31
        xp_base = ((size_t)(b0 + eb) * SS) * HH + (n0 + ec);
    }

    for (int t = 0; t < SS; ++t) {
        // ---- prefetch own Xp (plain load, independent of sync) ----
        float xp = 0.f;
        if (tid < 128) xp = out[xp_base + (size_t)t * HH];

        float a[64];
#pragma unroll
        for (int i = 0; i < 64; ++i) a[i] = 0.f;

        if (t == 0) {
#pragma unroll
            for (int j = 0; j < 4; ++j) {
                int f4 = tid + 256 * j;
                int r = f4 >> 8, c4 = (f4 & 255) * 4;
                *(float4*)&hs[r][c4] = *(const float4*)(h0 + c4);
            }
            __syncthreads();
            FMA_HALF(0)
            FMA_HALF(1)
        } else {
            // ---- tag-in-data poll: batched 8-load re-issue until all 16
            //      floats carry parity ((t-1)>>1)&1. Data arrives WITH the
            //      successful poll -> no flag RT, no separate stage RT. ----
            const ull* hsrc = (const ull*)hbuf + (size_t)((t - 1) & 1) * BB * 512;
            const unsigned pc = ((unsigned)(t - 1) >> 1) & 1u;
            ull w[8];
            for (;;) {
#pragma unroll
                for (int j = 0; j < 4; ++j)
                    w[j] = ALD(hsrc + (size_t)(b0 + j) * 512 + tid);
#pragma unroll
                for (int j = 0; j < 4; ++j)
                    w[4 + j] = ALD(hsrc + (size_t)(b0 + j) * 512 + 256 + tid);
                unsigned bad = 0;
#pragma unroll
                for (int j = 0; j < 8; ++j) {
                    bad |= (((unsigned)(w[j] >> 30)) ^ pc) & 1u;
                    bad |= (((unsigned)(w[j] >> 62)) ^ pc) & 1u;
                }
                if (!bad) break;
            }
#pragma unroll
            for (int j = 0; j < 4; ++j) {
                *(ull*)&hs[j][tid * 2] = w[j] & TAGMASK;
                *(ull*)&hs[j][512 + tid * 2] = w[4 + j] & TAGMASK;
            }
            __syncthreads();
            FMA_HALF(0)
            FMA_HALF(1)
        }

        // ---- folding in-wave reduce over kq ----
        int s = 64;
#pragma unroll
        for (int m = 1; m <= 32; m <<= 1) {
            const int hs_ = s >> 1;
            const bool hi = (lane & m) != 0;
#pragma unroll
            for (int i = 0; i < hs_; ++i) {
                float lo = a[i], hg = a[i + hs_];
                a[i]       = hi ? hg : lo;
                a[i + hs_] = hi ? lo : hg;
            }
#pragma unroll
            for (int i = 0; i < hs_; ++i) a[i] += __shfl_xor(a[i + hs_], m, 64);
            s = hs_;
        }

        red[wv][lane] = a[0];
        __syncthreads();

        // ---- epilogue: finalize, write out (plain), linearize into hout ----
        if (tid < 128) {
            const int l = tid & 63;
            const int nss = tid >> 6;
            float v = red[nss * 2][l] + red[nss * 2 + 1][l];
            float hv = tanhf(v + xp);
            out[xp_base + (size_t)t * HH] = hv;  // plain (write-only in-kernel)
            hout[eb][ec] = hv;
        }
        __syncthreads();

        // ---- publish: 64 contiguous 8B stores, bit30 of each float = step
        //      parity (t>>1)&1. Validity rides inside the word: no ack, no
        //      flag. |h|<=1 -> bit30 is 0 pre-tag (exact recovery on read). ----
        if (tid < 64) {
            const int r  = tid >> 4;   // 0..3
            const int c2 = tid & 15;   // 0..15 (x2 floats = 32 cols)
            const ull pp = (ull)(((unsigned)t >> 1) & 1u);
            ull u = *(const ull*)&hout[r][c2 * 2];
            u |= (pp << 30) | (pp << 62);
            __hip_atomic_store(
                (ull*)hbuf + (size_t)(t & 1) * BB * 512 +
                    (size_t)(b0 + r) * 512 + (n0 >> 1) + c2,
                u, __ATOMIC_RELAXED, __HIP_MEMORY_SCOPE_AGENT);
        }
        // no trailing barrier: next step's tag-poll self-validates.
    }
}

// ---------------- fallback path (tiny ws): multi-launch steps ----------------
__global__ __launch_bounds__(256) void h0wh(const float* __restrict__ Wh,
                                            const float* __restrict__ h0,
                                            float* __restrict__ c) {
    const int g = blockIdx.x;
    const int n = threadIdx.x * 4;
    float4 a = {0.f, 0.f, 0.f, 0.f};
    for (int kk = 0; kk < 16; ++kk) {
        int k = g * 16 + kk;
        float hv = h0[k];
        float4 w = *(const float4*)(Wh + (size_t)k * HH + n);
        a.x += hv * w.x; a.y += hv * w.y; a.z += hv * w.z; a.w += hv * w.w;
    }
    atomicAdd(&c[n + 0], a.x);
    atomicAdd(&c[n + 1], a.y);
    atomicAdd(&c[n + 2], a.z);
    atomicAdd(&c[n + 3], a.w);
}

__global__ __launch_bounds__(256) void t0_kernel(float* __restrict__ out,
                                                 const float* __restrict__ c) {
    const int idx = blockIdx.x * 256 + threadIdx.x;
    const int b = idx >> 10;
    const int n = idx & 1023;
    const size_t p = (size_t)b * SS * HH + n;
    out[p] = tanhf(out[p] + c[n]);
}

__global__ __launch_bounds__(256) void rnn_step(const float* __restrict__ Wh,
                                                float* __restrict__ out, int t) {
    __shared__ float hsl[8][1028];
    __shared__ float ps[256];
    const int tid = threadIdx.x;
    const int n0 = blockIdx.x * 16;
    const int b0 = blockIdx.y * 8;
    for (int i = tid; i < 8 * 256; i += 256) {
        int r = i >> 8;
        int c = (i & 255) << 2;
        *(float4*)&hsl[r][c] =
            *(const float4*)(out + ((size_t)(b0 + r) * SS + (t - 1)) * HH + c);
    }
    __syncthreads();
    const int nl = tid & 15;
    const int bl = (tid >> 4) & 7;
    const int half_ = tid >> 7;
    const int n = n0 + nl;
    float acc = 0.f;
    const float* hrow = &hsl[bl][half_ * 512];
    const float* wcol = Wh + (size_t)(half_ * 512) * HH + n;
#pragma unroll 4
    for (int k = 0; k < 512; k += 4) {
        float4 h4 = *(const float4*)(hrow + k);
        acc += h4.x * wcol[(size_t)(k + 0) * HH];
        acc += h4.y * wcol[(size_t)(k + 1) * HH];
        acc += h4.z * wcol[(size_t)(k + 2) * HH];
        acc += h4.w * wcol[(size_t)(k + 3) * HH];
    }
    ps[tid] = acc;
    __syncthreads();
    if (tid < 128) {
        const size_t obase = ((size_t)(b0 + bl) * SS + t) * HH + n;
        out[obase] = tanhf(out[obase] + ps[tid] + ps[tid + 128]);
    }
}

extern "C" void kernel_launch(void* const* d_in, const int* in_sizes, int n_in,
                              void* d_out, int out_size, void* d_ws, size_t ws_size,
                              hipStream_t stream) {
    const float* x    = (const float*)d_in[0];
    const float* Wx   = (const float*)d_in[1];
    const float* Wh   = (const float*)d_in[2];
    const float* bias = (const float*)d_in[3];
    const float* h0   = (const float*)d_in[4];
    float* out = (float*)d_out;
    float* ws  = (float*)d_ws;

    // Phase 1: Xp = x@Wx + b -> d_out
    xw_gemm<<<dim3(8, 256), 256, 0, stream>>>(x, Wx, bias, out);

    // ws layout: hbuf 2*32*1024 floats (256 KB, tag-in-data) | WhT 1024^2 f
    const size_t need_persist = (size_t)(2 * BB * HH) * sizeof(float);
    const size_t need_wht     = need_persist + (size_t)HH * HH * sizeof(float);

    if (ws_size >= need_persist) {
        float* hbuf = ws;
        // erase stale tags from prior launches/poison: 0xFF -> bit30=1 = stale
        hipMemsetAsync(hbuf, 0xFF, need_persist, stream);

        const float* WhT = nullptr;
        if (ws_size >= need_wht) {
            float* whtp = ws + 2 * BB * HH;
            transpose_wh<<<dim3(32, 32), 256, 0, stream>>>(Wh, whtp);
            WhT = whtp;
        }

        void* kargs[] = {(void*)&Wh, (void*)&WhT, (void*)&h0, (void*)&out,
                         (void*)&hbuf};
        hipError_t rc = hipLaunchCooperativeKernel((const void*)rnn_persist,
                                                   dim3(WGN), dim3(256), kargs, 0,
                                                   stream);
        if (rc != hipSuccess) {
            rnn_persist<<<dim3(WGN), dim3(256), 0, stream>>>(Wh, WhT, h0, out,
                                                             hbuf);
        }
    } else {
        // emergency fallback: multi-launch (correct, slow)
        float* cvec = ws;  // 1024 floats
        hipMemsetAsync(cvec, 0, HH * sizeof(float), stream);
        h0wh<<<64, 256, 0, stream>>>(Wh, h0, cvec);
        t0_kernel<<<BB * HH / 256, 256, 0, stream>>>(out, cvec);
        for (int t = 1; t < SS; ++t)
            rnn_step<<<dim3(64, 4), 256, 0, stream>>>(Wh, out, t);
    }
}